// Round 4
// baseline (217.998 us; speedup 1.0000x reference)
//
#include <hip/hip_runtime.h>
#include <math.h>

// Problem constants: B=16, N=128, M=64, D=512, H=4, K=128, L=3
//
// relu(x*y) = (x*y + |x|*|y|)/2  (exact) -> every contraction over the
// [B,N,M,D] relu-hadamard tensor becomes a plain fp32 GEMM.
//
//   s[b,n,m,h] = sum_d w[n,d]*(r[m,d]*v2[h,d]) + |w[n,d]|*(|r[m,d]|*v2[h,d])
//                (v2 = v/2; lin_b/score_b cancel in softmax)
//   G[b,h,d]   = 1/2 * sum_m ( r[m,d]*accC[m,d] + |r[m,d]|*accA[m,d] )
//       accC = wts^T.w , accA = wts^T.|w|   (contraction over n)

// Workspace layout (floats)
#define OFF_W   0                         // w  [2048][512]
#define OFF_R   (2048*512)                // r  [1024][512]
#define OFF_V   (OFF_R + 1024*512)        // v2 [4][512]
#define OFF_S   (OFF_V + 2048)            // wts^T [64 bh][128 n][64 m]
#define OFF_G   (OFF_S + 64*8192)         // G  [64 bh][512]
#define OFF_SW  (OFF_G + 64*512)          // SW quarter-sums [64 bh][4]
// total: 2,132,224 floats = 8.53 MB

// ---------------------------------------------------------------------------
// Kernel 1: fused projections + prep_v
// blocks [0,256): w-GEMM, [256,384): r-GEMM, [384,392): v2 prep
// ---------------------------------------------------------------------------
__global__ __launch_bounds__(256) void proj_gemm(
    const float* __restrict__ word, const float* __restrict__ rel,
    const float* __restrict__ Wn_w, const float* __restrict__ Wn_b,
    const float* __restrict__ Wr_w, const float* __restrict__ Wr_b,
    const float* __restrict__ lin_w, const float* __restrict__ score_w,
    float* __restrict__ ws)
{
    int blk = blockIdx.x;
    if (blk >= 384) {
        // prep_v: v2[h][d] = 0.5 * sum_k lin_w[h,d,k]*score_w[h,k]
        int gid = (blk - 384) * 256 + threadIdx.x;   // 0..2047
        int h = gid >> 9, d = gid & 511;
        const float* lw = lin_w + (size_t)(h * 512 + d) * 128;
        const float* sw = score_w + h * 128;
        float acc = 0.f;
        #pragma unroll 4
        for (int k = 0; k < 128; k += 4) {
            float4 a = *(const float4*)(lw + k);
            float4 b = *(const float4*)(sw + k);
            acc = fmaf(a.x, b.x, acc); acc = fmaf(a.y, b.y, acc);
            acc = fmaf(a.z, b.z, acc); acc = fmaf(a.w, b.w, acc);
        }
        ws[OFF_V + h * 512 + d] = 0.5f * acc;
        return;
    }
    const float *A, *W, *bias;
    float* C;
    int rowTile, colTile;
    if (blk < 256) {
        A = word; W = Wn_w; bias = Wn_b; C = ws + OFF_W;
        rowTile = blk >> 3; colTile = blk & 7;
    } else {
        int b2 = blk - 256;
        A = rel; W = Wr_w; bias = Wr_b; C = ws + OFF_R;
        rowTile = b2 >> 3; colTile = b2 & 7;
    }
    const int row0 = rowTile * 64, col0 = colTile * 64;

    __shared__ float As[16][68];
    __shared__ float Bs[16][64];

    const int t  = threadIdx.x;
    const int tx = t & 15, ty = t >> 4;
    const int lr = t >> 2, lk = (t & 3) << 2;
    const int bk = t >> 4, bc = (t & 15) << 2;

    float acc[4][4] = {};

    for (int k0 = 0; k0 < 512; k0 += 16) {
        float4 a4 = *(const float4*)(A + (size_t)(row0 + lr) * 512 + k0 + lk);
        As[lk + 0][lr] = a4.x; As[lk + 1][lr] = a4.y;
        As[lk + 2][lr] = a4.z; As[lk + 3][lr] = a4.w;
        *(float4*)&Bs[bk][bc] = *(const float4*)(W + (size_t)(k0 + bk) * 512 + col0 + bc);
        __syncthreads();
        #pragma unroll
        for (int kk = 0; kk < 16; kk++) {
            float4 av = *(float4*)&As[kk][ty << 2];
            float4 bv = *(float4*)&Bs[kk][tx << 2];
            float aa[4] = {av.x, av.y, av.z, av.w};
            float bb[4] = {bv.x, bv.y, bv.z, bv.w};
            #pragma unroll
            for (int i = 0; i < 4; i++)
                #pragma unroll
                for (int j = 0; j < 4; j++)
                    acc[i][j] = fmaf(aa[i], bb[j], acc[i][j]);
        }
        __syncthreads();
    }
    float4 bv = *(const float4*)(bias + col0 + (tx << 2));
    float bb[4] = {bv.x, bv.y, bv.z, bv.w};
    #pragma unroll
    for (int i = 0; i < 4; i++) {
        float4 o;
        o.x = acc[i][0] + bb[0]; o.y = acc[i][1] + bb[1];
        o.z = acc[i][2] + bb[2]; o.w = acc[i][3] + bb[3];
        *(float4*)(C + (size_t)(row0 + (ty << 2) + i) * 512 + col0 + (tx << 2)) = o;
    }
}

// ---------------------------------------------------------------------------
// Kernel 2: scores GEMM + fused softmax (v2).
// grid = (b*4+h)*4+nq = 256 blocks, 256 threads, tile 64m x 32n, K=512.
// Register-prefetch double-buffer: ONE barrier per K-stage; |w| computed
// on the fly (not staged). Softmax parallel: 8 m-segments x 32 columns.
// Writes wts TRANSPOSED [n][m] + SW quarter sums.
// ---------------------------------------------------------------------------
__global__ __launch_bounds__(256) void scores_sm(
    const float* __restrict__ mask, float* __restrict__ ws)
{
    const int blk = blockIdx.x;
    const int nq = blk & 3, bh = blk >> 2, h = bh & 3, b = bh >> 2;
    const int n0 = nq * 32;

    const float* wbase = ws + OFF_W + (size_t)(b * 128) * 512;
    const float* rbase = ws + OFF_R + (size_t)(b * 64) * 512;
    float* wtsT = ws + OFF_S + (size_t)bh * 8192;   // [128 n][64 m]

    __shared__ float v2s[512];
    __shared__ float maskl[64];
    __shared__ float Arv[2][16][68];   // [k][m] : r*v2
    __shared__ float Ara[2][16][68];   // [k][m] : |r|*v2
    __shared__ float Wl[2][16][36];    // [k][n] : w
    __shared__ float sl[64][33];       // [m][n] scores / exp
    __shared__ float pmax[8][33], psum[8][33], pms[8][33];

    const int t = threadIdx.x;
    if (t < 128) *(float4*)&v2s[t * 4] = *(const float4*)(ws + OFF_V + h * 512 + t * 4);
    if (t < 64) maskl[t] = mask[b * 64 + t];

    const int tm = t & 15, tn = t >> 4;          // compute: 4m x 2n microtile
    const int sm = t >> 2, sk = (t & 3) * 4;     // A stage
    const int wn = t >> 2, wk = (t & 3) * 4;     // W stage (t<128)
    __syncthreads();

    // prologue: stage k0=0 into buf 0
    {
        float4 r4 = *(const float4*)(rbase + (size_t)sm * 512 + sk);
        float4 vv = *(const float4*)&v2s[sk];
        Arv[0][sk + 0][sm] = r4.x * vv.x; Ara[0][sk + 0][sm] = fabsf(r4.x) * vv.x;
        Arv[0][sk + 1][sm] = r4.y * vv.y; Ara[0][sk + 1][sm] = fabsf(r4.y) * vv.y;
        Arv[0][sk + 2][sm] = r4.z * vv.z; Ara[0][sk + 2][sm] = fabsf(r4.z) * vv.z;
        Arv[0][sk + 3][sm] = r4.w * vv.w; Ara[0][sk + 3][sm] = fabsf(r4.w) * vv.w;
        if (t < 128) {
            float4 w4 = *(const float4*)(wbase + (size_t)(n0 + wn) * 512 + wk);
            Wl[0][wk + 0][wn] = w4.x; Wl[0][wk + 1][wn] = w4.y;
            Wl[0][wk + 2][wn] = w4.z; Wl[0][wk + 3][wn] = w4.w;
        }
    }
    __syncthreads();

    float acc[4][2] = {};
    int buf = 0;
    for (int s = 0; s < 32; s++) {
        float4 r4n, w4n;
        const int k0n = (s + 1) * 16;
        if (s < 31) {
            r4n = *(const float4*)(rbase + (size_t)sm * 512 + k0n + sk);
            if (t < 128)
                w4n = *(const float4*)(wbase + (size_t)(n0 + wn) * 512 + k0n + wk);
        }
        #pragma unroll
        for (int kk = 0; kk < 16; kk++) {
            float4 rv = *(float4*)&Arv[buf][kk][tm * 4];
            float4 ra = *(float4*)&Ara[buf][kk][tm * 4];
            float2 wv = *(float2*)&Wl[buf][kk][tn * 2];
            float wax = fabsf(wv.x), way = fabsf(wv.y);
            acc[0][0] = fmaf(rv.x, wv.x, acc[0][0]); acc[0][0] = fmaf(ra.x, wax, acc[0][0]);
            acc[1][0] = fmaf(rv.y, wv.x, acc[1][0]); acc[1][0] = fmaf(ra.y, wax, acc[1][0]);
            acc[2][0] = fmaf(rv.z, wv.x, acc[2][0]); acc[2][0] = fmaf(ra.z, wax, acc[2][0]);
            acc[3][0] = fmaf(rv.w, wv.x, acc[3][0]); acc[3][0] = fmaf(ra.w, wax, acc[3][0]);
            acc[0][1] = fmaf(rv.x, wv.y, acc[0][1]); acc[0][1] = fmaf(ra.x, way, acc[0][1]);
            acc[1][1] = fmaf(rv.y, wv.y, acc[1][1]); acc[1][1] = fmaf(ra.y, way, acc[1][1]);
            acc[2][1] = fmaf(rv.z, wv.y, acc[2][1]); acc[2][1] = fmaf(ra.z, way, acc[2][1]);
            acc[3][1] = fmaf(rv.w, wv.y, acc[3][1]); acc[3][1] = fmaf(ra.w, way, acc[3][1]);
        }
        if (s < 31) {
            float4 vv = *(const float4*)&v2s[k0n + sk];
            const int nb = buf ^ 1;
            Arv[nb][sk + 0][sm] = r4n.x * vv.x; Ara[nb][sk + 0][sm] = fabsf(r4n.x) * vv.x;
            Arv[nb][sk + 1][sm] = r4n.y * vv.y; Ara[nb][sk + 1][sm] = fabsf(r4n.y) * vv.y;
            Arv[nb][sk + 2][sm] = r4n.z * vv.z; Ara[nb][sk + 2][sm] = fabsf(r4n.z) * vv.z;
            Arv[nb][sk + 3][sm] = r4n.w * vv.w; Ara[nb][sk + 3][sm] = fabsf(r4n.w) * vv.w;
            if (t < 128) {
                Wl[nb][wk + 0][wn] = w4n.x; Wl[nb][wk + 1][wn] = w4n.y;
                Wl[nb][wk + 2][wn] = w4n.z; Wl[nb][wk + 3][wn] = w4n.w;
            }
        }
        __syncthreads();
        buf ^= 1;
    }

    #pragma unroll
    for (int i = 0; i < 4; i++) {
        sl[tm * 4 + i][tn * 2 + 0] = acc[i][0];
        sl[tm * 4 + i][tn * 2 + 1] = acc[i][1];
    }
    __syncthreads();

    // parallel softmax: seg = m-octet, col = n
    const int col = t & 31, seg = t >> 5;
    {
        float mx = sl[seg * 8 + 0][col];
        #pragma unroll
        for (int q = 1; q < 8; q++) mx = fmaxf(mx, sl[seg * 8 + q][col]);
        pmax[seg][col] = mx;
    }
    __syncthreads();
    float gmx = pmax[0][col];
    #pragma unroll
    for (int q = 1; q < 8; q++) gmx = fmaxf(gmx, pmax[q][col]);
    float es[8], ps = 0.f, pm = 0.f;
    #pragma unroll
    for (int q = 0; q < 8; q++) {
        int m = seg * 8 + q;
        float e = expf(sl[m][col] - gmx);
        es[q] = e; ps += e; pm = fmaf(e, maskl[m], pm);
    }
    psum[seg][col] = ps; pms[seg][col] = pm;
    __syncthreads();
    float tot = psum[0][col];
    #pragma unroll
    for (int q = 1; q < 8; q++) tot += psum[q][col];
    const float inv = 1.0f / tot;
    float o[8];
    #pragma unroll
    for (int q = 0; q < 8; q++) o[q] = es[q] * inv * maskl[seg * 8 + q];
    float4 o0; o0.x = o[0]; o0.y = o[1]; o0.z = o[2]; o0.w = o[3];
    float4 o1; o1.x = o[4]; o1.y = o[5]; o1.z = o[6]; o1.w = o[7];
    *(float4*)(wtsT + (size_t)(n0 + col) * 64 + seg * 8)     = o0;
    *(float4*)(wtsT + (size_t)(n0 + col) * 64 + seg * 8 + 4) = o1;
    if (seg == 0) {                      // t < 32: SW quarter sum
        float pmt = pms[0][col];
        #pragma unroll
        for (int q = 1; q < 8; q++) pmt += pms[q][col];
        float swc = pmt * inv;
        #pragma unroll
        for (int off = 16; off > 0; off >>= 1)
            swc += __shfl_xor(swc, off);
        if (col == 0) ws[OFF_SW + bh * 4 + nq] = swc;
    }
}

// ---------------------------------------------------------------------------
// Kernel 3: G-step.  accC = wts^T.w, accA = wts^T.|w| (over n, K=128),
// epilogue: G[b,h,d] = 0.5 * sum_m ( r[m,d]*accC + |r[m,d]|*accA )
// grid = bh*8 + dtile = 512 blocks; tile 64m x 64d; no atomics.
// ---------------------------------------------------------------------------
__global__ __launch_bounds__(256) void gstep_kernel(float* __restrict__ ws)
{
    const int blk = blockIdx.x;
    const int dtile = blk & 7, bh = blk >> 3;
    const int b = bh >> 2;
    const int d0 = dtile * 64;
    const float* wtsT  = ws + OFF_S + (size_t)bh * 8192;        // [n][m]
    const float* wbase = ws + OFF_W + (size_t)(b * 128) * 512;
    const float* rbase = ws + OFF_R + (size_t)(b * 64) * 512;

    __shared__ float As[16][68];   // [n][m]
    __shared__ float Bs[16][68];   // [n][d]  w
    __shared__ float Ba[16][68];   // [n][d]  |w|
    __shared__ float red[16][68];

    const int t = threadIdx.x;
    const int tx = t & 15, ty = t >> 4;
    const int an_r = t >> 4, am4 = (t & 15) * 4;   // A stage (row n, m-quad)
    const int bn = t >> 4, bd4 = (t & 15) * 4;     // B stage

    float accC[4][4] = {}, accA[4][4] = {};

    for (int n0 = 0; n0 < 128; n0 += 16) {
        *(float4*)&As[an_r][am4] =
            *(const float4*)(wtsT + (size_t)(n0 + an_r) * 64 + am4);
        float4 b4 = *(const float4*)(wbase + (size_t)(n0 + bn) * 512 + d0 + bd4);
        *(float4*)&Bs[bn][bd4] = b4;
        float4 bb; bb.x = fabsf(b4.x); bb.y = fabsf(b4.y);
        bb.z = fabsf(b4.z); bb.w = fabsf(b4.w);
        *(float4*)&Ba[bn][bd4] = bb;
        __syncthreads();
        #pragma unroll
        for (int kk = 0; kk < 16; kk++) {
            float4 av  = *(float4*)&As[kk][ty * 4];
            float4 bv  = *(float4*)&Bs[kk][tx * 4];
            float4 bav = *(float4*)&Ba[kk][tx * 4];
            float av_[4]  = {av.x, av.y, av.z, av.w};
            float bv_[4]  = {bv.x, bv.y, bv.z, bv.w};
            float bav_[4] = {bav.x, bav.y, bav.z, bav.w};
            #pragma unroll
            for (int i = 0; i < 4; i++)
                #pragma unroll
                for (int j = 0; j < 4; j++) {
                    accC[i][j] = fmaf(av_[i], bv_[j],  accC[i][j]);
                    accA[i][j] = fmaf(av_[i], bav_[j], accA[i][j]);
                }
        }
        __syncthreads();
    }
    // epilogue: thread owns m = ty*4+i, d = d0 + tx*4+j
    float g0 = 0.f, g1 = 0.f, g2 = 0.f, g3 = 0.f;
    #pragma unroll
    for (int i = 0; i < 4; i++) {
        float4 rv = *(const float4*)(rbase + (size_t)(ty * 4 + i) * 512 + d0 + tx * 4);
        g0 = fmaf(rv.x, accC[i][0], g0); g0 = fmaf(fabsf(rv.x), accA[i][0], g0);
        g1 = fmaf(rv.y, accC[i][1], g1); g1 = fmaf(fabsf(rv.y), accA[i][1], g1);
        g2 = fmaf(rv.z, accC[i][2], g2); g2 = fmaf(fabsf(rv.z), accA[i][2], g2);
        g3 = fmaf(rv.w, accC[i][3], g3); g3 = fmaf(fabsf(rv.w), accA[i][3], g3);
    }
    float4 gg; gg.x = g0; gg.y = g1; gg.z = g2; gg.w = g3;
    *(float4*)&red[ty][tx * 4] = gg;
    __syncthreads();
    if (t < 64) {
        float s = 0.f;
        #pragma unroll
        for (int q = 0; q < 16; q++) s += red[q][t];
        ws[OFF_G + (size_t)bh * 512 + d0 + t] = 0.5f * s;
    }
}

// ---------------------------------------------------------------------------
// Kernel 4: per-batch epilogue: headmean -> final(+relu) -> logits.
// grid = 16 blocks; no atomics, no memset.
// ---------------------------------------------------------------------------
__global__ __launch_bounds__(256) void epilogue_kernel(
    const float* __restrict__ lin_w, const float* __restrict__ lin_b,
    const float* __restrict__ final_w, const float* __restrict__ final_b,
    const float* __restrict__ fc_w, const float* __restrict__ fc_b,
    const float* __restrict__ ws, float* __restrict__ out)
{
    const int b = blockIdx.x, t = threadIdx.x;
    __shared__ float Gs[2048];
    __shared__ float hs[512];
    __shared__ float os[512];
    __shared__ float SWs[4];

    const float* G = ws + OFF_G + (size_t)b * 2048;
    #pragma unroll
    for (int i = 0; i < 8; i++) Gs[t + 256 * i] = G[t + 256 * i];
    if (t < 4) {
        const float* swq = ws + OFF_SW + (size_t)(b * 4 + t) * 4;
        SWs[t] = (swq[0] + swq[1]) + (swq[2] + swq[3]);
    }
    __syncthreads();

    // headmean: 512 outputs, 2 per thread, 4-way unrolled accumulators
    #pragma unroll
    for (int i = 0; i < 2; i++) {
        int idx = t + 256 * i;
        int h = idx >> 7, k = idx & 127;
        const float* lwp = lin_w + ((size_t)h * 512) * 128 + k;
        const float* gp = Gs + h * 512;
        float a0 = 0.f, a1 = 0.f, a2 = 0.f, a3 = 0.f;
        for (int d = 0; d < 512; d += 4) {
            a0 = fmaf(gp[d + 0], lwp[(size_t)(d + 0) * 128], a0);
            a1 = fmaf(gp[d + 1], lwp[(size_t)(d + 1) * 128], a1);
            a2 = fmaf(gp[d + 2], lwp[(size_t)(d + 2) * 128], a2);
            a3 = fmaf(gp[d + 3], lwp[(size_t)(d + 3) * 128], a3);
        }
        float acc = (a0 + a1) + (a2 + a3) + lin_b[h * 128 + k] * SWs[h];
        hs[idx] = acc * (1.0f / 128.0f);
    }
    __syncthreads();

    // final: out = relu(hs @ final_w + final_b)
    #pragma unroll
    for (int i = 0; i < 2; i++) {
        int j = t + 256 * i;
        const float* fwp = final_w + j;
        float a0 = 0.f, a1 = 0.f, a2 = 0.f, a3 = 0.f;
        for (int d = 0; d < 512; d += 4) {
            a0 = fmaf(hs[d + 0], fwp[(size_t)(d + 0) * 512], a0);
            a1 = fmaf(hs[d + 1], fwp[(size_t)(d + 1) * 512], a1);
            a2 = fmaf(hs[d + 2], fwp[(size_t)(d + 2) * 512], a2);
            a3 = fmaf(hs[d + 3], fwp[(size_t)(d + 3) * 512], a3);
        }
        os[j] = fmaxf((a0 + a1) + (a2 + a3) + final_b[j], 0.f);
    }
    __syncthreads();

    // logits: 3 outputs, one wave-pair lane-group per output
    if (t < 192) {
        int l = t >> 6, ln = t & 63;
        float acc = 0.f;
        for (int i2 = ln; i2 < 512; i2 += 64)
            acc = fmaf(os[i2], fc_w[i2 * 3 + l], acc);
        #pragma unroll
        for (int off = 32; off > 0; off >>= 1)
            acc += __shfl_xor(acc, off);
        if (ln == 0) out[b * 3 + l] = acc + fc_b[l];
    }
}

// ---------------------------------------------------------------------------
extern "C" void kernel_launch(void* const* d_in, const int* in_sizes, int n_in,
                              void* d_out, int out_size, void* d_ws, size_t ws_size,
                              hipStream_t stream)
{
    const float* word    = (const float*)d_in[0];
    const float* rel     = (const float*)d_in[1];
    const float* mask    = (const float*)d_in[2];
    const float* Wn_w    = (const float*)d_in[3];
    const float* Wn_b    = (const float*)d_in[4];
    const float* Wr_w    = (const float*)d_in[5];
    const float* Wr_b    = (const float*)d_in[6];
    const float* lin_w   = (const float*)d_in[7];
    const float* lin_b   = (const float*)d_in[8];
    const float* score_w = (const float*)d_in[9];
    // d_in[10] score_b: cancels in softmax — unused
    const float* final_w = (const float*)d_in[11];
    const float* final_b = (const float*)d_in[12];
    const float* fc_w    = (const float*)d_in[13];
    const float* fc_b    = (const float*)d_in[14];
    float* ws  = (float*)d_ws;
    float* out = (float*)d_out;

    proj_gemm<<<392, 256, 0, stream>>>(word, rel, Wn_w, Wn_b, Wr_w, Wr_b,
                                       lin_w, score_w, ws);
    scores_sm<<<256, 256, 0, stream>>>(mask, ws);
    gstep_kernel<<<512, 256, 0, stream>>>(ws);
    epilogue_kernel<<<16, 256, 0, stream>>>(lin_w, lin_b, final_w, final_b,
                                            fc_w, fc_b, ws, out);
}

// Round 6
// 182.589 us; speedup vs baseline: 1.1939x; 1.1939x over previous
//
#include <hip/hip_runtime.h>
#include <math.h>

// Problem constants: B=16, N=128, M=64, D=512, H=4, K=128, L=3
//
// relu(x*y) = (x*y + |x|*|y|)/2  (exact) -> every contraction over the
// [B,N,M,D] relu-hadamard tensor becomes a plain fp32 GEMM.
//
//   s[b,n,m,h] = sum_d w[n,d]*(r[m,d]*v2[h,d]) + |w[n,d]|*(|r[m,d]|*v2[h,d])
//                (v2 = v/2; lin_b/score_b cancel in softmax)
//   G[b,h,d]   = 1/2 * sum_m ( r[m,d]*accC[m,d] + |r[m,d]|*accA[m,d] )
//       accC = wts^T.w , accA = wts^T.|w|   (contraction over n)

// Workspace layout (floats)
#define OFF_W   0                         // w  [2048][512]
#define OFF_R   (2048*512)                // r  [1024][512]
#define OFF_V   (OFF_R + 1024*512)        // v2 [4][512]
#define OFF_S   (OFF_V + 2048)            // wts^T [64 bh][128 n][64 m]
#define OFF_G   (OFF_S + 64*8192)         // G  [64 bh][512]
#define OFF_SW  (OFF_G + 64*512)          // SW quarter-sums [64 bh][4]
#define OFF_HM  (OFF_SW + 256)            // hm [16 b][512]
// total: 2,140,416 floats = 8.56 MB

// ---------------------------------------------------------------------------
// Kernel 1: fused projections + prep_v
// blocks [0,256): w-GEMM, [256,384): r-GEMM, [384,392): v2 prep
// ---------------------------------------------------------------------------
__global__ __launch_bounds__(256) void proj_gemm(
    const float* __restrict__ word, const float* __restrict__ rel,
    const float* __restrict__ Wn_w, const float* __restrict__ Wn_b,
    const float* __restrict__ Wr_w, const float* __restrict__ Wr_b,
    const float* __restrict__ lin_w, const float* __restrict__ score_w,
    float* __restrict__ ws)
{
    int blk = blockIdx.x;
    if (blk >= 384) {
        // prep_v: v2[h][d] = 0.5 * sum_k lin_w[h,d,k]*score_w[h,k]
        int gid = (blk - 384) * 256 + threadIdx.x;   // 0..2047
        int h = gid >> 9, d = gid & 511;
        const float* lw = lin_w + (size_t)(h * 512 + d) * 128;
        const float* sw = score_w + h * 128;
        float acc = 0.f;
        #pragma unroll 4
        for (int k = 0; k < 128; k += 4) {
            float4 a = *(const float4*)(lw + k);
            float4 b = *(const float4*)(sw + k);
            acc = fmaf(a.x, b.x, acc); acc = fmaf(a.y, b.y, acc);
            acc = fmaf(a.z, b.z, acc); acc = fmaf(a.w, b.w, acc);
        }
        ws[OFF_V + h * 512 + d] = 0.5f * acc;
        return;
    }
    const float *A, *W, *bias;
    float* C;
    int rowTile, colTile;
    if (blk < 256) {
        A = word; W = Wn_w; bias = Wn_b; C = ws + OFF_W;
        rowTile = blk >> 3; colTile = blk & 7;
    } else {
        int b2 = blk - 256;
        A = rel; W = Wr_w; bias = Wr_b; C = ws + OFF_R;
        rowTile = b2 >> 3; colTile = b2 & 7;
    }
    const int row0 = rowTile * 64, col0 = colTile * 64;

    __shared__ float As[16][68];
    __shared__ float Bs[16][64];

    const int t  = threadIdx.x;
    const int tx = t & 15, ty = t >> 4;
    const int lr = t >> 2, lk = (t & 3) << 2;
    const int bk = t >> 4, bc = (t & 15) << 2;

    float acc[4][4] = {};

    for (int k0 = 0; k0 < 512; k0 += 16) {
        float4 a4 = *(const float4*)(A + (size_t)(row0 + lr) * 512 + k0 + lk);
        As[lk + 0][lr] = a4.x; As[lk + 1][lr] = a4.y;
        As[lk + 2][lr] = a4.z; As[lk + 3][lr] = a4.w;
        *(float4*)&Bs[bk][bc] = *(const float4*)(W + (size_t)(k0 + bk) * 512 + col0 + bc);
        __syncthreads();
        #pragma unroll
        for (int kk = 0; kk < 16; kk++) {
            float4 av = *(float4*)&As[kk][ty << 2];
            float4 bv = *(float4*)&Bs[kk][tx << 2];
            float aa[4] = {av.x, av.y, av.z, av.w};
            float bb[4] = {bv.x, bv.y, bv.z, bv.w};
            #pragma unroll
            for (int i = 0; i < 4; i++)
                #pragma unroll
                for (int j = 0; j < 4; j++)
                    acc[i][j] = fmaf(aa[i], bb[j], acc[i][j]);
        }
        __syncthreads();
    }
    float4 bv = *(const float4*)(bias + col0 + (tx << 2));
    float bb[4] = {bv.x, bv.y, bv.z, bv.w};
    #pragma unroll
    for (int i = 0; i < 4; i++) {
        float4 o;
        o.x = acc[i][0] + bb[0]; o.y = acc[i][1] + bb[1];
        o.z = acc[i][2] + bb[2]; o.w = acc[i][3] + bb[3];
        *(float4*)(C + (size_t)(row0 + (ty << 2) + i) * 512 + col0 + (tx << 2)) = o;
    }
}

// ---------------------------------------------------------------------------
// Kernel 2: scores GEMM + fused softmax (v2, double-buffered).
// grid = (b*4+h)*4+nq = 256 blocks, 256 threads, tile 64m x 32n, K=512.
// Register-prefetch double-buffer: ONE barrier per K-stage; |w| computed
// on the fly. Softmax parallel: 8 m-segments x 32 columns.
// Writes wts TRANSPOSED [n][m] + SW quarter sums.
// ---------------------------------------------------------------------------
__global__ __launch_bounds__(256) void scores_sm(
    const float* __restrict__ mask, float* __restrict__ ws)
{
    const int blk = blockIdx.x;
    const int nq = blk & 3, bh = blk >> 2, h = bh & 3, b = bh >> 2;
    const int n0 = nq * 32;

    const float* wbase = ws + OFF_W + (size_t)(b * 128) * 512;
    const float* rbase = ws + OFF_R + (size_t)(b * 64) * 512;
    float* wtsT = ws + OFF_S + (size_t)bh * 8192;   // [128 n][64 m]

    __shared__ float v2s[512];
    __shared__ float maskl[64];
    __shared__ float Arv[2][16][68];   // [k][m] : r*v2
    __shared__ float Ara[2][16][68];   // [k][m] : |r|*v2
    __shared__ float Wl[2][16][36];    // [k][n] : w
    __shared__ float sl[64][33];       // [m][n] scores / exp
    __shared__ float pmax[8][33], psum[8][33], pms[8][33];

    const int t = threadIdx.x;
    if (t < 128) *(float4*)&v2s[t * 4] = *(const float4*)(ws + OFF_V + h * 512 + t * 4);
    if (t < 64) maskl[t] = mask[b * 64 + t];

    const int tm = t & 15, tn = t >> 4;          // compute: 4m x 2n microtile
    const int sm = t >> 2, sk = (t & 3) * 4;     // A stage
    const int wn = t >> 2, wk = (t & 3) * 4;     // W stage (t<128)
    __syncthreads();

    // prologue: stage k0=0 into buf 0
    {
        float4 r4 = *(const float4*)(rbase + (size_t)sm * 512 + sk);
        float4 vv = *(const float4*)&v2s[sk];
        Arv[0][sk + 0][sm] = r4.x * vv.x; Ara[0][sk + 0][sm] = fabsf(r4.x) * vv.x;
        Arv[0][sk + 1][sm] = r4.y * vv.y; Ara[0][sk + 1][sm] = fabsf(r4.y) * vv.y;
        Arv[0][sk + 2][sm] = r4.z * vv.z; Ara[0][sk + 2][sm] = fabsf(r4.z) * vv.z;
        Arv[0][sk + 3][sm] = r4.w * vv.w; Ara[0][sk + 3][sm] = fabsf(r4.w) * vv.w;
        if (t < 128) {
            float4 w4 = *(const float4*)(wbase + (size_t)(n0 + wn) * 512 + wk);
            Wl[0][wk + 0][wn] = w4.x; Wl[0][wk + 1][wn] = w4.y;
            Wl[0][wk + 2][wn] = w4.z; Wl[0][wk + 3][wn] = w4.w;
        }
    }
    __syncthreads();

    float acc[4][2] = {};
    int buf = 0;
    for (int s = 0; s < 32; s++) {
        float4 r4n, w4n;
        const int k0n = (s + 1) * 16;
        if (s < 31) {
            r4n = *(const float4*)(rbase + (size_t)sm * 512 + k0n + sk);
            if (t < 128)
                w4n = *(const float4*)(wbase + (size_t)(n0 + wn) * 512 + k0n + wk);
        }
        #pragma unroll
        for (int kk = 0; kk < 16; kk++) {
            float4 rv = *(float4*)&Arv[buf][kk][tm * 4];
            float4 ra = *(float4*)&Ara[buf][kk][tm * 4];
            float2 wv = *(float2*)&Wl[buf][kk][tn * 2];
            float wax = fabsf(wv.x), way = fabsf(wv.y);
            acc[0][0] = fmaf(rv.x, wv.x, acc[0][0]); acc[0][0] = fmaf(ra.x, wax, acc[0][0]);
            acc[1][0] = fmaf(rv.y, wv.x, acc[1][0]); acc[1][0] = fmaf(ra.y, wax, acc[1][0]);
            acc[2][0] = fmaf(rv.z, wv.x, acc[2][0]); acc[2][0] = fmaf(ra.z, wax, acc[2][0]);
            acc[3][0] = fmaf(rv.w, wv.x, acc[3][0]); acc[3][0] = fmaf(ra.w, wax, acc[3][0]);
            acc[0][1] = fmaf(rv.x, wv.y, acc[0][1]); acc[0][1] = fmaf(ra.x, way, acc[0][1]);
            acc[1][1] = fmaf(rv.y, wv.y, acc[1][1]); acc[1][1] = fmaf(ra.y, way, acc[1][1]);
            acc[2][1] = fmaf(rv.z, wv.y, acc[2][1]); acc[2][1] = fmaf(ra.z, way, acc[2][1]);
            acc[3][1] = fmaf(rv.w, wv.y, acc[3][1]); acc[3][1] = fmaf(ra.w, way, acc[3][1]);
        }
        if (s < 31) {
            float4 vv = *(const float4*)&v2s[k0n + sk];
            const int nb = buf ^ 1;
            Arv[nb][sk + 0][sm] = r4n.x * vv.x; Ara[nb][sk + 0][sm] = fabsf(r4n.x) * vv.x;
            Arv[nb][sk + 1][sm] = r4n.y * vv.y; Ara[nb][sk + 1][sm] = fabsf(r4n.y) * vv.y;
            Arv[nb][sk + 2][sm] = r4n.z * vv.z; Ara[nb][sk + 2][sm] = fabsf(r4n.z) * vv.z;
            Arv[nb][sk + 3][sm] = r4n.w * vv.w; Ara[nb][sk + 3][sm] = fabsf(r4n.w) * vv.w;
            if (t < 128) {
                Wl[nb][wk + 0][wn] = w4n.x; Wl[nb][wk + 1][wn] = w4n.y;
                Wl[nb][wk + 2][wn] = w4n.z; Wl[nb][wk + 3][wn] = w4n.w;
            }
        }
        __syncthreads();
        buf ^= 1;
    }

    #pragma unroll
    for (int i = 0; i < 4; i++) {
        sl[tm * 4 + i][tn * 2 + 0] = acc[i][0];
        sl[tm * 4 + i][tn * 2 + 1] = acc[i][1];
    }
    __syncthreads();

    // parallel softmax: seg = m-octet, col = n
    const int col = t & 31, seg = t >> 5;
    {
        float mx = sl[seg * 8 + 0][col];
        #pragma unroll
        for (int q = 1; q < 8; q++) mx = fmaxf(mx, sl[seg * 8 + q][col]);
        pmax[seg][col] = mx;
    }
    __syncthreads();
    float gmx = pmax[0][col];
    #pragma unroll
    for (int q = 1; q < 8; q++) gmx = fmaxf(gmx, pmax[q][col]);
    float es[8], ps = 0.f, pm = 0.f;
    #pragma unroll
    for (int q = 0; q < 8; q++) {
        int m = seg * 8 + q;
        float e = expf(sl[m][col] - gmx);
        es[q] = e; ps += e; pm = fmaf(e, maskl[m], pm);
    }
    psum[seg][col] = ps; pms[seg][col] = pm;
    __syncthreads();
    float tot = psum[0][col];
    #pragma unroll
    for (int q = 1; q < 8; q++) tot += psum[q][col];
    const float inv = 1.0f / tot;
    float o[8];
    #pragma unroll
    for (int q = 0; q < 8; q++) o[q] = es[q] * inv * maskl[seg * 8 + q];
    float4 o0; o0.x = o[0]; o0.y = o[1]; o0.z = o[2]; o0.w = o[3];
    float4 o1; o1.x = o[4]; o1.y = o[5]; o1.z = o[6]; o1.w = o[7];
    *(float4*)(wtsT + (size_t)(n0 + col) * 64 + seg * 8)     = o0;
    *(float4*)(wtsT + (size_t)(n0 + col) * 64 + seg * 8 + 4) = o1;
    if (seg == 0) {                      // t < 32: SW quarter sum
        float pmt = pms[0][col];
        #pragma unroll
        for (int q = 1; q < 8; q++) pmt += pms[q][col];
        float swc = pmt * inv;
        #pragma unroll
        for (int off = 16; off > 0; off >>= 1)
            swc += __shfl_xor(swc, off);
        if (col == 0) ws[OFF_SW + bh * 4 + nq] = swc;
    }
}

// ---------------------------------------------------------------------------
// Kernel 3: G-step.  accC = wts^T.w, accA = wts^T.|w| (over n, K=128),
// epilogue: G[b,h,d] = 0.5 * sum_m ( r[m,d]*accC + |r[m,d]|*accA )
// grid = bh*8 + dtile = 512 blocks; tile 64m x 64d; no atomics.
// ---------------------------------------------------------------------------
__global__ __launch_bounds__(256) void gstep_kernel(float* __restrict__ ws)
{
    const int blk = blockIdx.x;
    const int dtile = blk & 7, bh = blk >> 3;
    const int b = bh >> 2;
    const int d0 = dtile * 64;
    const float* wtsT  = ws + OFF_S + (size_t)bh * 8192;        // [n][m]
    const float* wbase = ws + OFF_W + (size_t)(b * 128) * 512;
    const float* rbase = ws + OFF_R + (size_t)(b * 64) * 512;

    __shared__ float As[16][68];   // [n][m]
    __shared__ float Bs[16][68];   // [n][d]  w
    __shared__ float Ba[16][68];   // [n][d]  |w|
    __shared__ float red[16][68];

    const int t = threadIdx.x;
    const int tx = t & 15, ty = t >> 4;
    const int an_r = t >> 4, am4 = (t & 15) * 4;   // A stage (row n, m-quad)
    const int bn = t >> 4, bd4 = (t & 15) * 4;     // B stage

    float accC[4][4] = {}, accA[4][4] = {};

    for (int n0 = 0; n0 < 128; n0 += 16) {
        *(float4*)&As[an_r][am4] =
            *(const float4*)(wtsT + (size_t)(n0 + an_r) * 64 + am4);
        float4 b4 = *(const float4*)(wbase + (size_t)(n0 + bn) * 512 + d0 + bd4);
        *(float4*)&Bs[bn][bd4] = b4;
        float4 bb; bb.x = fabsf(b4.x); bb.y = fabsf(b4.y);
        bb.z = fabsf(b4.z); bb.w = fabsf(b4.w);
        *(float4*)&Ba[bn][bd4] = bb;
        __syncthreads();
        #pragma unroll
        for (int kk = 0; kk < 16; kk++) {
            float4 av  = *(float4*)&As[kk][ty * 4];
            float4 bv  = *(float4*)&Bs[kk][tx * 4];
            float4 bav = *(float4*)&Ba[kk][tx * 4];
            float av_[4]  = {av.x, av.y, av.z, av.w};
            float bv_[4]  = {bv.x, bv.y, bv.z, bv.w};
            float bav_[4] = {bav.x, bav.y, bav.z, bav.w};
            #pragma unroll
            for (int i = 0; i < 4; i++)
                #pragma unroll
                for (int j = 0; j < 4; j++) {
                    accC[i][j] = fmaf(av_[i], bv_[j],  accC[i][j]);
                    accA[i][j] = fmaf(av_[i], bav_[j], accA[i][j]);
                }
        }
        __syncthreads();
    }
    // epilogue: thread owns m = ty*4+i, d = d0 + tx*4+j
    float g0 = 0.f, g1 = 0.f, g2 = 0.f, g3 = 0.f;
    #pragma unroll
    for (int i = 0; i < 4; i++) {
        float4 rv = *(const float4*)(rbase + (size_t)(ty * 4 + i) * 512 + d0 + tx * 4);
        g0 = fmaf(rv.x, accC[i][0], g0); g0 = fmaf(fabsf(rv.x), accA[i][0], g0);
        g1 = fmaf(rv.y, accC[i][1], g1); g1 = fmaf(fabsf(rv.y), accA[i][1], g1);
        g2 = fmaf(rv.z, accC[i][2], g2); g2 = fmaf(fabsf(rv.z), accA[i][2], g2);
        g3 = fmaf(rv.w, accC[i][3], g3); g3 = fmaf(fabsf(rv.w), accA[i][3], g3);
    }
    float4 gg; gg.x = g0; gg.y = g1; gg.z = g2; gg.w = g3;
    *(float4*)&red[ty][tx * 4] = gg;
    __syncthreads();
    if (t < 64) {
        float s = 0.f;
        #pragma unroll
        for (int q = 0; q < 16; q++) s += red[q][t];
        ws[OFF_G + (size_t)bh * 512 + d0 + t] = 0.5f * s;
    }
}

// ---------------------------------------------------------------------------
// Kernel 4: headmean.  grid = bh*4 + kt = 256 blocks, 32 k each, 8-way d-split.
// hm[b, h*128+k] = ( sum_d G[bh][d]*lin_w[h,d,k] + lin_b[h,k]*SW[bh] ) / 128
// ---------------------------------------------------------------------------
__global__ __launch_bounds__(256) void headmean_kernel(
    const float* __restrict__ lin_w, const float* __restrict__ lin_b,
    float* __restrict__ ws)
{
    const int blk = blockIdx.x;
    const int kt = blk & 3, bh = blk >> 2, b = bh >> 2, h = bh & 3;
    const int t = threadIdx.x;
    const int dg = t >> 5, kk = t & 31;
    const int k = kt * 32 + kk;

    __shared__ float Gs[512];
    __shared__ float red[8][33];

    Gs[t]       = ws[OFF_G + (size_t)bh * 512 + t];
    Gs[t + 256] = ws[OFF_G + (size_t)bh * 512 + t + 256];
    __syncthreads();

    const float* lwp = lin_w + ((size_t)h * 512 + dg * 64) * 128 + k;
    const float* gp = Gs + dg * 64;
    float acc = 0.f;
    #pragma unroll 8
    for (int d = 0; d < 64; d++)
        acc = fmaf(gp[d], lwp[(size_t)d * 128], acc);
    red[dg][kk] = acc;
    __syncthreads();
    if (t < 32) {
        float s = 0.f;
        #pragma unroll
        for (int q = 0; q < 8; q++) s += red[q][t];
        const float SWv = ws[OFF_SW + bh * 4 + 0] + ws[OFF_SW + bh * 4 + 1]
                        + ws[OFF_SW + bh * 4 + 2] + ws[OFF_SW + bh * 4 + 3];
        s = fmaf(lin_b[h * 128 + kt * 32 + t], SWv, s);
        ws[OFF_HM + (size_t)b * 512 + h * 128 + kt * 32 + t] = s * (1.0f / 128.0f);
    }
}

// ---------------------------------------------------------------------------
// Kernel 5: final + fused logits.  grid = b*16 + jt = 256 blocks, 32 j each.
// os_j = relu(hm[b]. final_w[:,j] + final_b[j]);
// atomicAdd partial logits (out zeroed by memset; fc_b added by jt==0 blocks).
// ---------------------------------------------------------------------------
__global__ __launch_bounds__(256) void final_logits(
    const float* __restrict__ final_w, const float* __restrict__ final_b,
    const float* __restrict__ fc_w, const float* __restrict__ fc_b,
    const float* __restrict__ ws, float* __restrict__ out)
{
    const int blk = blockIdx.x;
    const int jt = blk & 15, b = blk >> 4;
    const int t = threadIdx.x;
    const int dg = t >> 5, jj = t & 31;
    const int j = jt * 32 + jj;

    __shared__ float hs[512];
    __shared__ float red[8][33];
    __shared__ float osl[32];

    hs[t]       = ws[OFF_HM + (size_t)b * 512 + t];
    hs[t + 256] = ws[OFF_HM + (size_t)b * 512 + t + 256];
    __syncthreads();

    const float* fwp = final_w + (size_t)(dg * 64) * 512 + j;
    const float* hp = hs + dg * 64;
    float acc = 0.f;
    #pragma unroll 8
    for (int d = 0; d < 64; d++)
        acc = fmaf(hp[d], fwp[(size_t)d * 512], acc);
    red[dg][jj] = acc;
    __syncthreads();
    if (t < 32) {
        float s = 0.f;
        #pragma unroll
        for (int q = 0; q < 8; q++) s += red[q][t];
        osl[t] = fmaxf(s + final_b[jt * 32 + t], 0.f);
    }
    __syncthreads();
    if (t < 96) {
        const int l = t >> 5, j2 = t & 31;
        float val = osl[j2] * fc_w[(jt * 32 + j2) * 3 + l];
        #pragma unroll
        for (int off = 16; off > 0; off >>= 1)
            val += __shfl_xor(val, off);
        if (j2 == 0) atomicAdd(out + b * 3 + l, val);
    }
    if (jt == 0 && t < 3) atomicAdd(out + b * 3 + t, fc_b[t]);
}

// ---------------------------------------------------------------------------
extern "C" void kernel_launch(void* const* d_in, const int* in_sizes, int n_in,
                              void* d_out, int out_size, void* d_ws, size_t ws_size,
                              hipStream_t stream)
{
    const float* word    = (const float*)d_in[0];
    const float* rel     = (const float*)d_in[1];
    const float* mask    = (const float*)d_in[2];
    const float* Wn_w    = (const float*)d_in[3];
    const float* Wn_b    = (const float*)d_in[4];
    const float* Wr_w    = (const float*)d_in[5];
    const float* Wr_b    = (const float*)d_in[6];
    const float* lin_w   = (const float*)d_in[7];
    const float* lin_b   = (const float*)d_in[8];
    const float* score_w = (const float*)d_in[9];
    // d_in[10] score_b: cancels in softmax — unused
    const float* final_w = (const float*)d_in[11];
    const float* final_b = (const float*)d_in[12];
    const float* fc_w    = (const float*)d_in[13];
    const float* fc_b    = (const float*)d_in[14];
    float* ws  = (float*)d_ws;
    float* out = (float*)d_out;

    // logits are accumulated atomically -> zero the 192-byte output
    hipMemsetAsync(out, 0, 16 * 3 * sizeof(float), stream);

    proj_gemm<<<392, 256, 0, stream>>>(word, rel, Wn_w, Wn_b, Wr_w, Wr_b,
                                       lin_w, score_w, ws);
    scores_sm<<<256, 256, 0, stream>>>(mask, ws);
    gstep_kernel<<<512, 256, 0, stream>>>(ws);
    headmean_kernel<<<256, 256, 0, stream>>>(lin_w, lin_b, ws);
    final_logits<<<256, 256, 0, stream>>>(final_w, final_b, fc_w, fc_b, ws, out);
}

// Round 7
// 172.972 us; speedup vs baseline: 1.2603x; 1.0556x over previous
//
#include <hip/hip_runtime.h>
#include <math.h>

// Problem constants: B=16, N=128, M=64, D=512, H=4, K=128, L=3
//
// relu(x*y) = (x*y + |x|*|y|)/2  (exact) -> every contraction over the
// [B,N,M,D] relu-hadamard tensor becomes a plain fp32 GEMM.
// Second-term trick (exact, sign-magnitude fp):
//   |r*v2| * copysign(w, v2) = |r| * v2 * |w|
// so neither |r|*v2 nor |w| needs to be staged in LDS.

// Workspace layout (floats)
#define OFF_W   0                         // w  [2048][512]
#define OFF_R   (2048*512)                // r  [1024][512]
#define OFF_V   (OFF_R + 1024*512)        // v2 [4][512]
#define OFF_S   (OFF_V + 2048)            // wts^T [64 bh][128 n][64 m]
#define OFF_G   (OFF_S + 64*8192)         // (layout hole; G now LDS-only)
#define OFF_SW  (OFF_G + 64*512)          // SW quarter-sums [64 bh][4]
#define OFF_HM  (OFF_SW + 256)            // hm [16 b][512] (atomic-accumulated)
// total: 2,140,416 floats = 8.56 MB

// ---------------------------------------------------------------------------
// Kernel 1: fused projections + prep_v + out-zero
// blocks [0,128): w-GEMM 128x64 tiles, [128,192): r-GEMM, [192,200): v2 prep
// 8m x 4n microtile, BK=16, register-prefetch single-barrier double-buffer.
// ---------------------------------------------------------------------------
__global__ __launch_bounds__(256) void proj_gemm(
    const float* __restrict__ word, const float* __restrict__ rel,
    const float* __restrict__ Wn_w, const float* __restrict__ Wn_b,
    const float* __restrict__ Wr_w, const float* __restrict__ Wr_b,
    const float* __restrict__ lin_w, const float* __restrict__ score_w,
    float* __restrict__ ws, float* __restrict__ out)
{
    const int blk = blockIdx.x;
    const int t = threadIdx.x;
    if (blk >= 192) {
        if (blk == 192 && t < 48) out[t] = 0.f;   // zero logits accumulator
        // prep_v: v2[h][d] = 0.5 * sum_k lin_w[h,d,k]*score_w[h,k]
        int gid = (blk - 192) * 256 + t;           // 0..2047
        int h = gid >> 9, d = gid & 511;
        const float* lw = lin_w + (size_t)(h * 512 + d) * 128;
        const float* sw = score_w + h * 128;
        float acc = 0.f;
        #pragma unroll 4
        for (int k = 0; k < 128; k += 4) {
            float4 a = *(const float4*)(lw + k);
            float4 b = *(const float4*)(sw + k);
            acc = fmaf(a.x, b.x, acc); acc = fmaf(a.y, b.y, acc);
            acc = fmaf(a.z, b.z, acc); acc = fmaf(a.w, b.w, acc);
        }
        ws[OFF_V + h * 512 + d] = 0.5f * acc;
        return;
    }
    const float *A, *W, *bias;
    float* C;
    int rowTile, colTile;
    if (blk < 128) {
        A = word; W = Wn_w; bias = Wn_b; C = ws + OFF_W;
        rowTile = blk >> 3; colTile = blk & 7;      // 16 x 8
    } else {
        int b2 = blk - 128;
        A = rel; W = Wr_w; bias = Wr_b; C = ws + OFF_R;
        rowTile = b2 >> 3; colTile = b2 & 7;        // 8 x 8
    }
    const int row0 = rowTile * 128, col0 = colTile * 64;

    __shared__ float As[2][16][132];   // [k][m]
    __shared__ float Bs[2][16][68];    // [k][n]

    const int tx = t & 15, ty = t >> 4;        // n-quad / m-octet
    const int ar = t >> 1, ks = (t & 1) * 8;   // A stage: row, k-octet
    const int bk = t >> 4, bc = (t & 15) * 4;  // B stage

    float acc[8][4] = {};

    // prologue: stage k0=0 into buf 0
    {
        float4 aA = *(const float4*)(A + (size_t)(row0 + ar) * 512 + ks);
        float4 aB = *(const float4*)(A + (size_t)(row0 + ar) * 512 + ks + 4);
        As[0][ks + 0][ar] = aA.x; As[0][ks + 1][ar] = aA.y;
        As[0][ks + 2][ar] = aA.z; As[0][ks + 3][ar] = aA.w;
        As[0][ks + 4][ar] = aB.x; As[0][ks + 5][ar] = aB.y;
        As[0][ks + 6][ar] = aB.z; As[0][ks + 7][ar] = aB.w;
        *(float4*)&Bs[0][bk][bc] = *(const float4*)(W + (size_t)bk * 512 + col0 + bc);
    }
    __syncthreads();

    int buf = 0;
    for (int s = 0; s < 32; s++) {
        float4 aAn, aBn, bn4;
        if (s < 31) {
            const int k0n = (s + 1) * 16;
            aAn = *(const float4*)(A + (size_t)(row0 + ar) * 512 + k0n + ks);
            aBn = *(const float4*)(A + (size_t)(row0 + ar) * 512 + k0n + ks + 4);
            bn4 = *(const float4*)(W + (size_t)(k0n + bk) * 512 + col0 + bc);
        }
        #pragma unroll
        for (int kk = 0; kk < 16; kk++) {
            float4 a0 = *(float4*)&As[buf][kk][ty * 8];
            float4 a1 = *(float4*)&As[buf][kk][ty * 8 + 4];
            float4 bv = *(float4*)&Bs[buf][kk][tx * 4];
            float am[8] = {a0.x, a0.y, a0.z, a0.w, a1.x, a1.y, a1.z, a1.w};
            float bb[4] = {bv.x, bv.y, bv.z, bv.w};
            #pragma unroll
            for (int i = 0; i < 8; i++)
                #pragma unroll
                for (int j = 0; j < 4; j++)
                    acc[i][j] = fmaf(am[i], bb[j], acc[i][j]);
        }
        if (s < 31) {
            const int nb = buf ^ 1;
            As[nb][ks + 0][ar] = aAn.x; As[nb][ks + 1][ar] = aAn.y;
            As[nb][ks + 2][ar] = aAn.z; As[nb][ks + 3][ar] = aAn.w;
            As[nb][ks + 4][ar] = aBn.x; As[nb][ks + 5][ar] = aBn.y;
            As[nb][ks + 6][ar] = aBn.z; As[nb][ks + 7][ar] = aBn.w;
            *(float4*)&Bs[nb][bk][bc] = bn4;
        }
        __syncthreads();
        buf ^= 1;
    }
    float4 bv4 = *(const float4*)(bias + col0 + tx * 4);
    #pragma unroll
    for (int i = 0; i < 8; i++) {
        float4 o;
        o.x = acc[i][0] + bv4.x; o.y = acc[i][1] + bv4.y;
        o.z = acc[i][2] + bv4.z; o.w = acc[i][3] + bv4.w;
        *(float4*)(C + (size_t)(row0 + ty * 8 + i) * 512 + col0 + tx * 4) = o;
    }
}

// ---------------------------------------------------------------------------
// Kernel 2: scores GEMM + fused softmax (v3).
// grid = (b*4+h)*4+nq = 256 blocks, tile 64m x 32n, K=512, dbuf 1-barrier.
// Only r*v2 and w staged; |.| terms via fabs/copysign in-register (exact).
// Writes wts^T [n][m], SW quarter sums, and zeroes its hm[32] slice.
// ---------------------------------------------------------------------------
__global__ __launch_bounds__(256) void scores_sm(
    const float* __restrict__ mask, float* __restrict__ ws)
{
    const int blk = blockIdx.x;
    const int nq = blk & 3, bh = blk >> 2, h = bh & 3, b = bh >> 2;
    const int n0 = nq * 32;

    const float* wbase = ws + OFF_W + (size_t)(b * 128) * 512;
    const float* rbase = ws + OFF_R + (size_t)(b * 64) * 512;
    float* wtsT = ws + OFF_S + (size_t)bh * 8192;   // [128 n][64 m]

    __shared__ float v2s[512];
    __shared__ float maskl[64];
    __shared__ float Arv[2][16][68];   // [k][m] : r*v2
    __shared__ float Wl[2][16][36];    // [k][n] : w
    __shared__ float sl[64][33];       // [m][n] scores / exp
    __shared__ float pmax[8][33], psum[8][33], pms[8][33];

    const int t = threadIdx.x;
    if (t < 128) *(float4*)&v2s[t * 4] = *(const float4*)(ws + OFF_V + h * 512 + t * 4);
    if (t < 64) maskl[t] = mask[b * 64 + t];
    // zero this block's hm slice (consumed by gstep's atomics, stream-ordered)
    if (t < 32) ws[OFF_HM + (size_t)b * 512 + h * 128 + n0 + t] = 0.f;

    const int tm = t & 15, tn = t >> 4;          // compute: 4m x 2n microtile
    const int sm = t >> 2, sk = (t & 3) * 4;     // A stage
    const int wn = t >> 2, wk = (t & 3) * 4;     // W stage (t<128)
    __syncthreads();

    // prologue: stage k0=0 into buf 0
    {
        float4 r4 = *(const float4*)(rbase + (size_t)sm * 512 + sk);
        float4 vv = *(const float4*)&v2s[sk];
        Arv[0][sk + 0][sm] = r4.x * vv.x;
        Arv[0][sk + 1][sm] = r4.y * vv.y;
        Arv[0][sk + 2][sm] = r4.z * vv.z;
        Arv[0][sk + 3][sm] = r4.w * vv.w;
        if (t < 128) {
            float4 w4 = *(const float4*)(wbase + (size_t)(n0 + wn) * 512 + wk);
            Wl[0][wk + 0][wn] = w4.x; Wl[0][wk + 1][wn] = w4.y;
            Wl[0][wk + 2][wn] = w4.z; Wl[0][wk + 3][wn] = w4.w;
        }
    }
    __syncthreads();

    float acc[4][2] = {};
    int buf = 0;
    for (int s = 0; s < 32; s++) {
        float4 r4n, w4n;
        const int k0n = (s + 1) * 16;
        if (s < 31) {
            r4n = *(const float4*)(rbase + (size_t)sm * 512 + k0n + sk);
            if (t < 128)
                w4n = *(const float4*)(wbase + (size_t)(n0 + wn) * 512 + k0n + wk);
        }
        #pragma unroll
        for (int kk = 0; kk < 16; kk++) {
            float4 rv = *(float4*)&Arv[buf][kk][tm * 4];
            float2 wv = *(float2*)&Wl[buf][kk][tn * 2];
            float sv = v2s[s * 16 + kk];
            float wax = copysignf(wv.x, sv), way = copysignf(wv.y, sv);
            float r0 = fabsf(rv.x), r1 = fabsf(rv.y);
            float r2 = fabsf(rv.z), r3 = fabsf(rv.w);
            acc[0][0] = fmaf(rv.x, wv.x, acc[0][0]); acc[0][0] = fmaf(r0, wax, acc[0][0]);
            acc[1][0] = fmaf(rv.y, wv.x, acc[1][0]); acc[1][0] = fmaf(r1, wax, acc[1][0]);
            acc[2][0] = fmaf(rv.z, wv.x, acc[2][0]); acc[2][0] = fmaf(r2, wax, acc[2][0]);
            acc[3][0] = fmaf(rv.w, wv.x, acc[3][0]); acc[3][0] = fmaf(r3, wax, acc[3][0]);
            acc[0][1] = fmaf(rv.x, wv.y, acc[0][1]); acc[0][1] = fmaf(r0, way, acc[0][1]);
            acc[1][1] = fmaf(rv.y, wv.y, acc[1][1]); acc[1][1] = fmaf(r1, way, acc[1][1]);
            acc[2][1] = fmaf(rv.z, wv.y, acc[2][1]); acc[2][1] = fmaf(r2, way, acc[2][1]);
            acc[3][1] = fmaf(rv.w, wv.y, acc[3][1]); acc[3][1] = fmaf(r3, way, acc[3][1]);
        }
        if (s < 31) {
            float4 vv = *(const float4*)&v2s[k0n + sk];
            const int nb = buf ^ 1;
            Arv[nb][sk + 0][sm] = r4n.x * vv.x;
            Arv[nb][sk + 1][sm] = r4n.y * vv.y;
            Arv[nb][sk + 2][sm] = r4n.z * vv.z;
            Arv[nb][sk + 3][sm] = r4n.w * vv.w;
            if (t < 128) {
                Wl[nb][wk + 0][wn] = w4n.x; Wl[nb][wk + 1][wn] = w4n.y;
                Wl[nb][wk + 2][wn] = w4n.z; Wl[nb][wk + 3][wn] = w4n.w;
            }
        }
        __syncthreads();
        buf ^= 1;
    }

    #pragma unroll
    for (int i = 0; i < 4; i++) {
        sl[tm * 4 + i][tn * 2 + 0] = acc[i][0];
        sl[tm * 4 + i][tn * 2 + 1] = acc[i][1];
    }
    __syncthreads();

    // parallel softmax: seg = m-octet, col = n
    const int col = t & 31, seg = t >> 5;
    {
        float mx = sl[seg * 8 + 0][col];
        #pragma unroll
        for (int q = 1; q < 8; q++) mx = fmaxf(mx, sl[seg * 8 + q][col]);
        pmax[seg][col] = mx;
    }
    __syncthreads();
    float gmx = pmax[0][col];
    #pragma unroll
    for (int q = 1; q < 8; q++) gmx = fmaxf(gmx, pmax[q][col]);
    float es[8], ps = 0.f, pm = 0.f;
    #pragma unroll
    for (int q = 0; q < 8; q++) {
        int m = seg * 8 + q;
        float e = expf(sl[m][col] - gmx);
        es[q] = e; ps += e; pm = fmaf(e, maskl[m], pm);
    }
    psum[seg][col] = ps; pms[seg][col] = pm;
    __syncthreads();
    float tot = psum[0][col];
    #pragma unroll
    for (int q = 1; q < 8; q++) tot += psum[q][col];
    const float inv = 1.0f / tot;
    float o[8];
    #pragma unroll
    for (int q = 0; q < 8; q++) o[q] = es[q] * inv * maskl[seg * 8 + q];
    float4 o0; o0.x = o[0]; o0.y = o[1]; o0.z = o[2]; o0.w = o[3];
    float4 o1; o1.x = o[4]; o1.y = o[5]; o1.z = o[6]; o1.w = o[7];
    *(float4*)(wtsT + (size_t)(n0 + col) * 64 + seg * 8)     = o0;
    *(float4*)(wtsT + (size_t)(n0 + col) * 64 + seg * 8 + 4) = o1;
    if (seg == 0) {                      // t < 32: SW quarter sum
        float pmt = pms[0][col];
        #pragma unroll
        for (int q = 1; q < 8; q++) pmt += pms[q][col];
        float swc = pmt * inv;
        #pragma unroll
        for (int off = 16; off > 0; off >>= 1)
            swc += __shfl_xor(swc, off);
        if (col == 0) ws[OFF_SW + bh * 4 + nq] = swc;
    }
}

// ---------------------------------------------------------------------------
// Kernel 3: G-step + fused headmean partial.
// accC = wts^T.w, accA = wts^T.|w| (|w| via in-register fabs; dbuf 1-barrier);
// G-tile (64 d) -> LDS; then each block atomicAdds its 128-k headmean
// partial (scaled 1/128; dtile 0 adds lin_b*SW). grid = bh*8+dtile = 512.
// ---------------------------------------------------------------------------
__global__ __launch_bounds__(256) void gstep_kernel(
    const float* __restrict__ lin_w, const float* __restrict__ lin_b,
    float* __restrict__ ws)
{
    const int blk = blockIdx.x;
    const int dtile = blk & 7, bh = blk >> 3;
    const int b = bh >> 2, h = bh & 3;
    const int d0 = dtile * 64;
    const float* wtsT  = ws + OFF_S + (size_t)bh * 8192;        // [n][m]
    const float* wbase = ws + OFF_W + (size_t)(b * 128) * 512;
    const float* rbase = ws + OFF_R + (size_t)(b * 64) * 512;

    __shared__ float As[2][16][68];   // [n][m]
    __shared__ float Bs[2][16][68];   // [n][d]  w
    __shared__ float red[16][68];
    __shared__ float Gs[64];
    __shared__ float red2[128];

    const int t = threadIdx.x;
    const int tx = t & 15, ty = t >> 4;
    const int an_r = t >> 4, am4 = (t & 15) * 4;   // A stage
    const int bn = t >> 4, bd4 = (t & 15) * 4;     // B stage

    float accC[4][4] = {}, accA[4][4] = {};

    // prologue: stage n0=0
    *(float4*)&As[0][an_r][am4] = *(const float4*)(wtsT + (size_t)an_r * 64 + am4);
    *(float4*)&Bs[0][bn][bd4]   = *(const float4*)(wbase + (size_t)bn * 512 + d0 + bd4);
    __syncthreads();

    int buf = 0;
    for (int s = 0; s < 8; s++) {
        float4 a4n, b4n;
        if (s < 7) {
            const int n0n = (s + 1) * 16;
            a4n = *(const float4*)(wtsT + (size_t)(n0n + an_r) * 64 + am4);
            b4n = *(const float4*)(wbase + (size_t)(n0n + bn) * 512 + d0 + bd4);
        }
        #pragma unroll
        for (int kk = 0; kk < 16; kk++) {
            float4 av = *(float4*)&As[buf][kk][ty * 4];
            float4 bv = *(float4*)&Bs[buf][kk][tx * 4];
            float av_[4] = {av.x, av.y, av.z, av.w};
            float bv_[4] = {bv.x, bv.y, bv.z, bv.w};
            float ba_[4] = {fabsf(bv.x), fabsf(bv.y), fabsf(bv.z), fabsf(bv.w)};
            #pragma unroll
            for (int i = 0; i < 4; i++)
                #pragma unroll
                for (int j = 0; j < 4; j++) {
                    accC[i][j] = fmaf(av_[i], bv_[j], accC[i][j]);
                    accA[i][j] = fmaf(av_[i], ba_[j], accA[i][j]);
                }
        }
        if (s < 7) {
            const int nb = buf ^ 1;
            *(float4*)&As[nb][an_r][am4] = a4n;
            *(float4*)&Bs[nb][bn][bd4]   = b4n;
        }
        __syncthreads();
        buf ^= 1;
    }
    // epilogue: thread owns m = ty*4+i, d = d0 + tx*4+j
    float g0 = 0.f, g1 = 0.f, g2 = 0.f, g3 = 0.f;
    #pragma unroll
    for (int i = 0; i < 4; i++) {
        float4 rv = *(const float4*)(rbase + (size_t)(ty * 4 + i) * 512 + d0 + tx * 4);
        g0 = fmaf(rv.x, accC[i][0], g0); g0 = fmaf(fabsf(rv.x), accA[i][0], g0);
        g1 = fmaf(rv.y, accC[i][1], g1); g1 = fmaf(fabsf(rv.y), accA[i][1], g1);
        g2 = fmaf(rv.z, accC[i][2], g2); g2 = fmaf(fabsf(rv.z), accA[i][2], g2);
        g3 = fmaf(rv.w, accC[i][3], g3); g3 = fmaf(fabsf(rv.w), accA[i][3], g3);
    }
    float4 gg; gg.x = g0; gg.y = g1; gg.z = g2; gg.w = g3;
    *(float4*)&red[ty][tx * 4] = gg;
    __syncthreads();
    if (t < 64) {
        float s = 0.f;
        #pragma unroll
        for (int q = 0; q < 16; q++) s += red[q][t];
        Gs[t] = 0.5f * s;                 // G[bh][d0+t], LDS-only
    }
    __syncthreads();

    // fused headmean partial: hm[b, h*128+k] += (Gtile . lin_w_tile)/128
    const int k = t & 127, dh = t >> 7;
    const float* lwp = lin_w + ((size_t)h * 512 + d0 + dh * 32) * 128 + k;
    const float* gp = Gs + dh * 32;
    float acc2 = 0.f;
    #pragma unroll 8
    for (int d = 0; d < 32; d++)
        acc2 = fmaf(gp[d], lwp[(size_t)d * 128], acc2);
    if (dh) red2[k] = acc2;
    __syncthreads();
    if (!dh) {
        float p = acc2 + red2[k];
        if (dtile == 0) {
            const float SWv = ws[OFF_SW + bh * 4 + 0] + ws[OFF_SW + bh * 4 + 1]
                            + ws[OFF_SW + bh * 4 + 2] + ws[OFF_SW + bh * 4 + 3];
            p = fmaf(lin_b[h * 128 + k], SWv, p);
        }
        atomicAdd(&ws[OFF_HM + (size_t)b * 512 + h * 128 + k], p * (1.0f / 128.0f));
    }
}

// ---------------------------------------------------------------------------
// Kernel 4: final + fused logits.  grid = b*16 + jt = 256 blocks, 32 j each.
// os_j = relu(hm[b]. final_w[:,j] + final_b[j]);
// atomicAdd partial logits (out zeroed by proj_gemm; fc_b added by jt==0).
// ---------------------------------------------------------------------------
__global__ __launch_bounds__(256) void final_logits(
    const float* __restrict__ final_w, const float* __restrict__ final_b,
    const float* __restrict__ fc_w, const float* __restrict__ fc_b,
    const float* __restrict__ ws, float* __restrict__ out)
{
    const int blk = blockIdx.x;
    const int jt = blk & 15, b = blk >> 4;
    const int t = threadIdx.x;
    const int dg = t >> 5, jj = t & 31;
    const int j = jt * 32 + jj;

    __shared__ float hs[512];
    __shared__ float red[8][33];
    __shared__ float osl[32];

    hs[t]       = ws[OFF_HM + (size_t)b * 512 + t];
    hs[t + 256] = ws[OFF_HM + (size_t)b * 512 + t + 256];
    __syncthreads();

    const float* fwp = final_w + (size_t)(dg * 64) * 512 + j;
    const float* hp = hs + dg * 64;
    float acc = 0.f;
    #pragma unroll 8
    for (int d = 0; d < 64; d++)
        acc = fmaf(hp[d], fwp[(size_t)d * 512], acc);
    red[dg][jj] = acc;
    __syncthreads();
    if (t < 32) {
        float s = 0.f;
        #pragma unroll
        for (int q = 0; q < 8; q++) s += red[q][t];
        osl[t] = fmaxf(s + final_b[jt * 32 + t], 0.f);
    }
    __syncthreads();
    if (t < 96) {
        const int l = t >> 5, j2 = t & 31;
        float val = osl[j2] * fc_w[(jt * 32 + j2) * 3 + l];
        #pragma unroll
        for (int off = 16; off > 0; off >>= 1)
            val += __shfl_xor(val, off);
        if (j2 == 0) atomicAdd(out + b * 3 + l, val);
    }
    if (jt == 0 && t < 3) atomicAdd(out + b * 3 + t, fc_b[t]);
}

// ---------------------------------------------------------------------------
extern "C" void kernel_launch(void* const* d_in, const int* in_sizes, int n_in,
                              void* d_out, int out_size, void* d_ws, size_t ws_size,
                              hipStream_t stream)
{
    const float* word    = (const float*)d_in[0];
    const float* rel     = (const float*)d_in[1];
    const float* mask    = (const float*)d_in[2];
    const float* Wn_w    = (const float*)d_in[3];
    const float* Wn_b    = (const float*)d_in[4];
    const float* Wr_w    = (const float*)d_in[5];
    const float* Wr_b    = (const float*)d_in[6];
    const float* lin_w   = (const float*)d_in[7];
    const float* lin_b   = (const float*)d_in[8];
    const float* score_w = (const float*)d_in[9];
    // d_in[10] score_b: cancels in softmax — unused
    const float* final_w = (const float*)d_in[11];
    const float* final_b = (const float*)d_in[12];
    const float* fc_w    = (const float*)d_in[13];
    const float* fc_b    = (const float*)d_in[14];
    float* ws  = (float*)d_ws;
    float* out = (float*)d_out;

    // 4 dispatches, no memsets: out zeroed by proj_gemm (blk 192),
    // hm zeroed by scores_sm — all stream-ordered before their consumers.
    proj_gemm<<<200, 256, 0, stream>>>(word, rel, Wn_w, Wn_b, Wr_w, Wr_b,
                                       lin_w, score_w, ws, out);
    scores_sm<<<256, 256, 0, stream>>>(mask, ws);
    gstep_kernel<<<512, 256, 0, stream>>>(lin_w, lin_b, ws);
    final_logits<<<256, 256, 0, stream>>>(final_w, final_b, fc_w, fc_b, ws, out);
}

// Round 8
// 170.245 us; speedup vs baseline: 1.2805x; 1.0160x over previous
//
#include <hip/hip_runtime.h>
#include <math.h>

// Problem constants: B=16, N=128, M=64, D=512, H=4, K=128, L=3
//
// relu(x*y) = (x*y + |x|*|y|)/2  (exact) -> every contraction over the
// [B,N,M,D] relu-hadamard tensor becomes a plain fp32 GEMM.

// Workspace layout (floats)
#define OFF_W   0                         // w  [2048][512]
#define OFF_R   (2048*512)                // r  [1024][512]
#define OFF_V   (OFF_R + 1024*512)        // v2 [4][512]
#define OFF_S   (OFF_V + 2048)            // wts^T [64 bh][128 n][64 m]
#define OFF_G   (OFF_S + 64*8192)         // (layout hole; G is LDS-only now)
#define OFF_SW  (OFF_G + 64*512)          // SW quarter-sums [64 bh][4]
#define OFF_HM  (OFF_SW + 256)            // hm [16 b][512] (atomic-accumulated)
// total: 2,140,416 floats = 8.56 MB

// ---------------------------------------------------------------------------
// Kernel 1: fused projections + prep_v + out-zero
// blocks [0,256): w-GEMM 64x64 tiles, [256,384): r-GEMM, [384,392): v2 prep
// 4m x 4n microtile, BK=16, register-prefetch single-barrier double-buffer.
// Full-machine grid (384 GEMM blocks) + best issue density.
// ---------------------------------------------------------------------------
__global__ __launch_bounds__(256) void proj_gemm(
    const float* __restrict__ word, const float* __restrict__ rel,
    const float* __restrict__ Wn_w, const float* __restrict__ Wn_b,
    const float* __restrict__ Wr_w, const float* __restrict__ Wr_b,
    const float* __restrict__ lin_w, const float* __restrict__ score_w,
    float* __restrict__ ws, float* __restrict__ out)
{
    const int blk = blockIdx.x;
    const int t = threadIdx.x;
    if (blk >= 384) {
        if (blk == 384 && t < 48) out[t] = 0.f;   // zero logits accumulator
        // prep_v: v2[h][d] = 0.5 * sum_k lin_w[h,d,k]*score_w[h,k]
        int gid = (blk - 384) * 256 + t;           // 0..2047
        int h = gid >> 9, d = gid & 511;
        const float* lw = lin_w + (size_t)(h * 512 + d) * 128;
        const float* sw = score_w + h * 128;
        float acc = 0.f;
        #pragma unroll 4
        for (int k = 0; k < 128; k += 4) {
            float4 a = *(const float4*)(lw + k);
            float4 b = *(const float4*)(sw + k);
            acc = fmaf(a.x, b.x, acc); acc = fmaf(a.y, b.y, acc);
            acc = fmaf(a.z, b.z, acc); acc = fmaf(a.w, b.w, acc);
        }
        ws[OFF_V + h * 512 + d] = 0.5f * acc;
        return;
    }
    const float *A, *W, *bias;
    float* C;
    int rowTile, colTile;
    if (blk < 256) {
        A = word; W = Wn_w; bias = Wn_b; C = ws + OFF_W;
        rowTile = blk >> 3; colTile = blk & 7;      // 32 x 8
    } else {
        int b2 = blk - 256;
        A = rel; W = Wr_w; bias = Wr_b; C = ws + OFF_R;
        rowTile = b2 >> 3; colTile = b2 & 7;        // 16 x 8
    }
    const int row0 = rowTile * 64, col0 = colTile * 64;

    __shared__ float As[2][16][68];   // [k][m]
    __shared__ float Bs[2][16][68];   // [k][n]

    const int tx = t & 15, ty = t >> 4;        // n-quad / m-quad
    const int lr = t >> 2, lk = (t & 3) << 2;  // A stage: row, k-quad
    const int bk = t >> 4, bc = (t & 15) << 2; // B stage

    float acc[4][4] = {};

    // prologue: stage k0=0 into buf 0
    {
        float4 a4 = *(const float4*)(A + (size_t)(row0 + lr) * 512 + lk);
        As[0][lk + 0][lr] = a4.x; As[0][lk + 1][lr] = a4.y;
        As[0][lk + 2][lr] = a4.z; As[0][lk + 3][lr] = a4.w;
        *(float4*)&Bs[0][bk][bc] = *(const float4*)(W + (size_t)bk * 512 + col0 + bc);
    }
    __syncthreads();

    int buf = 0;
    for (int s = 0; s < 32; s++) {
        float4 a4n, b4n;
        if (s < 31) {
            const int k0n = (s + 1) * 16;
            a4n = *(const float4*)(A + (size_t)(row0 + lr) * 512 + k0n + lk);
            b4n = *(const float4*)(W + (size_t)(k0n + bk) * 512 + col0 + bc);
        }
        #pragma unroll
        for (int kk = 0; kk < 16; kk++) {
            float4 av = *(float4*)&As[buf][kk][ty << 2];
            float4 bv = *(float4*)&Bs[buf][kk][tx << 2];
            float aa[4] = {av.x, av.y, av.z, av.w};
            float bb[4] = {bv.x, bv.y, bv.z, bv.w};
            #pragma unroll
            for (int i = 0; i < 4; i++)
                #pragma unroll
                for (int j = 0; j < 4; j++)
                    acc[i][j] = fmaf(aa[i], bb[j], acc[i][j]);
        }
        if (s < 31) {
            const int nb = buf ^ 1;
            As[nb][lk + 0][lr] = a4n.x; As[nb][lk + 1][lr] = a4n.y;
            As[nb][lk + 2][lr] = a4n.z; As[nb][lk + 3][lr] = a4n.w;
            *(float4*)&Bs[nb][bk][bc] = b4n;
        }
        __syncthreads();
        buf ^= 1;
    }
    float4 bv4 = *(const float4*)(bias + col0 + (tx << 2));
    #pragma unroll
    for (int i = 0; i < 4; i++) {
        float4 o;
        o.x = acc[i][0] + bv4.x; o.y = acc[i][1] + bv4.y;
        o.z = acc[i][2] + bv4.z; o.w = acc[i][3] + bv4.w;
        *(float4*)(C + (size_t)(row0 + (ty << 2) + i) * 512 + col0 + (tx << 2)) = o;
    }
}

// ---------------------------------------------------------------------------
// Kernel 2: scores GEMM + fused softmax (v4).
// grid = (b*4+h)*4+nq = 256 blocks, tile 64m x 32n, K=512, dbuf 1-barrier.
// Staged: Arv = r*v2, Ara = |r|*v2, Wl = w; |w| via 2 in-register fabs.
// Per-kk issue: 16 FMA + 2 fabs + 3 LDS reads (best VALU density).
// Writes wts^T [n][m], SW quarter sums, and zeroes its hm[32] slice.
// ---------------------------------------------------------------------------
__global__ __launch_bounds__(256) void scores_sm(
    const float* __restrict__ mask, float* __restrict__ ws)
{
    const int blk = blockIdx.x;
    const int nq = blk & 3, bh = blk >> 2, h = bh & 3, b = bh >> 2;
    const int n0 = nq * 32;

    const float* wbase = ws + OFF_W + (size_t)(b * 128) * 512;
    const float* rbase = ws + OFF_R + (size_t)(b * 64) * 512;
    float* wtsT = ws + OFF_S + (size_t)bh * 8192;   // [128 n][64 m]

    __shared__ float v2s[512];
    __shared__ float maskl[64];
    __shared__ float Arv[2][16][68];   // [k][m] : r*v2
    __shared__ float Ara[2][16][68];   // [k][m] : |r|*v2
    __shared__ float Wl[2][16][36];    // [k][n] : w
    __shared__ float sl[64][33];       // [m][n] scores / exp
    __shared__ float pmax[8][33], psum[8][33], pms[8][33];

    const int t = threadIdx.x;
    if (t < 128) *(float4*)&v2s[t * 4] = *(const float4*)(ws + OFF_V + h * 512 + t * 4);
    if (t < 64) maskl[t] = mask[b * 64 + t];
    // zero this block's hm slice (consumed by gstep's atomics, stream-ordered)
    if (t < 32) ws[OFF_HM + (size_t)b * 512 + h * 128 + n0 + t] = 0.f;

    const int tm = t & 15, tn = t >> 4;          // compute: 4m x 2n microtile
    const int sm = t >> 2, sk = (t & 3) * 4;     // A stage
    const int wn = t >> 2, wk = (t & 3) * 4;     // W stage (t<128)
    __syncthreads();

    // prologue: stage k0=0 into buf 0
    {
        float4 r4 = *(const float4*)(rbase + (size_t)sm * 512 + sk);
        float4 vv = *(const float4*)&v2s[sk];
        Arv[0][sk + 0][sm] = r4.x * vv.x; Ara[0][sk + 0][sm] = fabsf(r4.x) * vv.x;
        Arv[0][sk + 1][sm] = r4.y * vv.y; Ara[0][sk + 1][sm] = fabsf(r4.y) * vv.y;
        Arv[0][sk + 2][sm] = r4.z * vv.z; Ara[0][sk + 2][sm] = fabsf(r4.z) * vv.z;
        Arv[0][sk + 3][sm] = r4.w * vv.w; Ara[0][sk + 3][sm] = fabsf(r4.w) * vv.w;
        if (t < 128) {
            float4 w4 = *(const float4*)(wbase + (size_t)(n0 + wn) * 512 + wk);
            Wl[0][wk + 0][wn] = w4.x; Wl[0][wk + 1][wn] = w4.y;
            Wl[0][wk + 2][wn] = w4.z; Wl[0][wk + 3][wn] = w4.w;
        }
    }
    __syncthreads();

    float acc[4][2] = {};
    int buf = 0;
    for (int s = 0; s < 32; s++) {
        float4 r4n, w4n;
        const int k0n = (s + 1) * 16;
        if (s < 31) {
            r4n = *(const float4*)(rbase + (size_t)sm * 512 + k0n + sk);
            if (t < 128)
                w4n = *(const float4*)(wbase + (size_t)(n0 + wn) * 512 + k0n + wk);
        }
        #pragma unroll
        for (int kk = 0; kk < 16; kk++) {
            float4 rv = *(float4*)&Arv[buf][kk][tm * 4];
            float4 ra = *(float4*)&Ara[buf][kk][tm * 4];
            float2 wv = *(float2*)&Wl[buf][kk][tn * 2];
            float wax = fabsf(wv.x), way = fabsf(wv.y);
            acc[0][0] = fmaf(rv.x, wv.x, acc[0][0]); acc[0][0] = fmaf(ra.x, wax, acc[0][0]);
            acc[1][0] = fmaf(rv.y, wv.x, acc[1][0]); acc[1][0] = fmaf(ra.y, wax, acc[1][0]);
            acc[2][0] = fmaf(rv.z, wv.x, acc[2][0]); acc[2][0] = fmaf(ra.z, wax, acc[2][0]);
            acc[3][0] = fmaf(rv.w, wv.x, acc[3][0]); acc[3][0] = fmaf(ra.w, wax, acc[3][0]);
            acc[0][1] = fmaf(rv.x, wv.y, acc[0][1]); acc[0][1] = fmaf(ra.x, way, acc[0][1]);
            acc[1][1] = fmaf(rv.y, wv.y, acc[1][1]); acc[1][1] = fmaf(ra.y, way, acc[1][1]);
            acc[2][1] = fmaf(rv.z, wv.y, acc[2][1]); acc[2][1] = fmaf(ra.z, way, acc[2][1]);
            acc[3][1] = fmaf(rv.w, wv.y, acc[3][1]); acc[3][1] = fmaf(ra.w, way, acc[3][1]);
        }
        if (s < 31) {
            float4 vv = *(const float4*)&v2s[k0n + sk];
            const int nb = buf ^ 1;
            Arv[nb][sk + 0][sm] = r4n.x * vv.x; Ara[nb][sk + 0][sm] = fabsf(r4n.x) * vv.x;
            Arv[nb][sk + 1][sm] = r4n.y * vv.y; Ara[nb][sk + 1][sm] = fabsf(r4n.y) * vv.y;
            Arv[nb][sk + 2][sm] = r4n.z * vv.z; Ara[nb][sk + 2][sm] = fabsf(r4n.z) * vv.z;
            Arv[nb][sk + 3][sm] = r4n.w * vv.w; Ara[nb][sk + 3][sm] = fabsf(r4n.w) * vv.w;
            if (t < 128) {
                Wl[nb][wk + 0][wn] = w4n.x; Wl[nb][wk + 1][wn] = w4n.y;
                Wl[nb][wk + 2][wn] = w4n.z; Wl[nb][wk + 3][wn] = w4n.w;
            }
        }
        __syncthreads();
        buf ^= 1;
    }

    #pragma unroll
    for (int i = 0; i < 4; i++) {
        sl[tm * 4 + i][tn * 2 + 0] = acc[i][0];
        sl[tm * 4 + i][tn * 2 + 1] = acc[i][1];
    }
    __syncthreads();

    // parallel softmax: seg = m-octet, col = n
    const int col = t & 31, seg = t >> 5;
    {
        float mx = sl[seg * 8 + 0][col];
        #pragma unroll
        for (int q = 1; q < 8; q++) mx = fmaxf(mx, sl[seg * 8 + q][col]);
        pmax[seg][col] = mx;
    }
    __syncthreads();
    float gmx = pmax[0][col];
    #pragma unroll
    for (int q = 1; q < 8; q++) gmx = fmaxf(gmx, pmax[q][col]);
    float es[8], ps = 0.f, pm = 0.f;
    #pragma unroll
    for (int q = 0; q < 8; q++) {
        int m = seg * 8 + q;
        float e = expf(sl[m][col] - gmx);
        es[q] = e; ps += e; pm = fmaf(e, maskl[m], pm);
    }
    psum[seg][col] = ps; pms[seg][col] = pm;
    __syncthreads();
    float tot = psum[0][col];
    #pragma unroll
    for (int q = 1; q < 8; q++) tot += psum[q][col];
    const float inv = 1.0f / tot;
    float o[8];
    #pragma unroll
    for (int q = 0; q < 8; q++) o[q] = es[q] * inv * maskl[seg * 8 + q];
    float4 o0; o0.x = o[0]; o0.y = o[1]; o0.z = o[2]; o0.w = o[3];
    float4 o1; o1.x = o[4]; o1.y = o[5]; o1.z = o[6]; o1.w = o[7];
    *(float4*)(wtsT + (size_t)(n0 + col) * 64 + seg * 8)     = o0;
    *(float4*)(wtsT + (size_t)(n0 + col) * 64 + seg * 8 + 4) = o1;
    if (seg == 0) {                      // t < 32: SW quarter sum
        float pmt = pms[0][col];
        #pragma unroll
        for (int q = 1; q < 8; q++) pmt += pms[q][col];
        float swc = pmt * inv;
        #pragma unroll
        for (int off = 16; off > 0; off >>= 1)
            swc += __shfl_xor(swc, off);
        if (col == 0) ws[OFF_SW + bh * 4 + nq] = swc;
    }
}

// ---------------------------------------------------------------------------
// Kernel 3: G-step + fused headmean partial.
// accC = wts^T.w, accA = wts^T.|w| (|w| via in-register fabs; dbuf 1-barrier);
// G-tile (64 d) -> LDS; then each block atomicAdds its 128-k headmean
// partial (scaled 1/128; dtile 0 adds lin_b*SW). grid = bh*8+dtile = 512.
// ---------------------------------------------------------------------------
__global__ __launch_bounds__(256) void gstep_kernel(
    const float* __restrict__ lin_w, const float* __restrict__ lin_b,
    float* __restrict__ ws)
{
    const int blk = blockIdx.x;
    const int dtile = blk & 7, bh = blk >> 3;
    const int b = bh >> 2, h = bh & 3;
    const int d0 = dtile * 64;
    const float* wtsT  = ws + OFF_S + (size_t)bh * 8192;        // [n][m]
    const float* wbase = ws + OFF_W + (size_t)(b * 128) * 512;
    const float* rbase = ws + OFF_R + (size_t)(b * 64) * 512;

    __shared__ float As[2][16][68];   // [n][m]
    __shared__ float Bs[2][16][68];   // [n][d]  w
    __shared__ float red[16][68];
    __shared__ float Gs[64];
    __shared__ float red2[128];

    const int t = threadIdx.x;
    const int tx = t & 15, ty = t >> 4;
    const int an_r = t >> 4, am4 = (t & 15) * 4;   // A stage
    const int bn = t >> 4, bd4 = (t & 15) * 4;     // B stage

    float accC[4][4] = {}, accA[4][4] = {};

    // prologue: stage n0=0
    *(float4*)&As[0][an_r][am4] = *(const float4*)(wtsT + (size_t)an_r * 64 + am4);
    *(float4*)&Bs[0][bn][bd4]   = *(const float4*)(wbase + (size_t)bn * 512 + d0 + bd4);
    __syncthreads();

    int buf = 0;
    for (int s = 0; s < 8; s++) {
        float4 a4n, b4n;
        if (s < 7) {
            const int n0n = (s + 1) * 16;
            a4n = *(const float4*)(wtsT + (size_t)(n0n + an_r) * 64 + am4);
            b4n = *(const float4*)(wbase + (size_t)(n0n + bn) * 512 + d0 + bd4);
        }
        #pragma unroll
        for (int kk = 0; kk < 16; kk++) {
            float4 av = *(float4*)&As[buf][kk][ty * 4];
            float4 bv = *(float4*)&Bs[buf][kk][tx * 4];
            float av_[4] = {av.x, av.y, av.z, av.w};
            float bv_[4] = {bv.x, bv.y, bv.z, bv.w};
            float ba_[4] = {fabsf(bv.x), fabsf(bv.y), fabsf(bv.z), fabsf(bv.w)};
            #pragma unroll
            for (int i = 0; i < 4; i++)
                #pragma unroll
                for (int j = 0; j < 4; j++) {
                    accC[i][j] = fmaf(av_[i], bv_[j], accC[i][j]);
                    accA[i][j] = fmaf(av_[i], ba_[j], accA[i][j]);
                }
        }
        if (s < 7) {
            const int nb = buf ^ 1;
            *(float4*)&As[nb][an_r][am4] = a4n;
            *(float4*)&Bs[nb][bn][bd4]   = b4n;
        }
        __syncthreads();
        buf ^= 1;
    }
    // epilogue: thread owns m = ty*4+i, d = d0 + tx*4+j
    float g0 = 0.f, g1 = 0.f, g2 = 0.f, g3 = 0.f;
    #pragma unroll
    for (int i = 0; i < 4; i++) {
        float4 rv = *(const float4*)(rbase + (size_t)(ty * 4 + i) * 512 + d0 + tx * 4);
        g0 = fmaf(rv.x, accC[i][0], g0); g0 = fmaf(fabsf(rv.x), accA[i][0], g0);
        g1 = fmaf(rv.y, accC[i][1], g1); g1 = fmaf(fabsf(rv.y), accA[i][1], g1);
        g2 = fmaf(rv.z, accC[i][2], g2); g2 = fmaf(fabsf(rv.z), accA[i][2], g2);
        g3 = fmaf(rv.w, accC[i][3], g3); g3 = fmaf(fabsf(rv.w), accA[i][3], g3);
    }
    float4 gg; gg.x = g0; gg.y = g1; gg.z = g2; gg.w = g3;
    *(float4*)&red[ty][tx * 4] = gg;
    __syncthreads();
    if (t < 64) {
        float s = 0.f;
        #pragma unroll
        for (int q = 0; q < 16; q++) s += red[q][t];
        Gs[t] = 0.5f * s;                 // G[bh][d0+t], LDS-only
    }
    __syncthreads();

    // fused headmean partial: hm[b, h*128+k] += (Gtile . lin_w_tile)/128
    const int k = t & 127, dh = t >> 7;
    const float* lwp = lin_w + ((size_t)h * 512 + d0 + dh * 32) * 128 + k;
    const float* gp = Gs + dh * 32;
    float acc2 = 0.f;
    #pragma unroll 8
    for (int d = 0; d < 32; d++)
        acc2 = fmaf(gp[d], lwp[(size_t)d * 128], acc2);
    if (dh) red2[k] = acc2;
    __syncthreads();
    if (!dh) {
        float p = acc2 + red2[k];
        if (dtile == 0) {
            const float SWv = ws[OFF_SW + bh * 4 + 0] + ws[OFF_SW + bh * 4 + 1]
                            + ws[OFF_SW + bh * 4 + 2] + ws[OFF_SW + bh * 4 + 3];
            p = fmaf(lin_b[h * 128 + k], SWv, p);
        }
        atomicAdd(&ws[OFF_HM + (size_t)b * 512 + h * 128 + k], p * (1.0f / 128.0f));
    }
}

// ---------------------------------------------------------------------------
// Kernel 4: final + fused logits.  grid = b*16 + jt = 256 blocks, 32 j each.
// os_j = relu(hm[b]. final_w[:,j] + final_b[j]);
// atomicAdd partial logits (out zeroed by proj_gemm; fc_b added by jt==0).
// ---------------------------------------------------------------------------
__global__ __launch_bounds__(256) void final_logits(
    const float* __restrict__ final_w, const float* __restrict__ final_b,
    const float* __restrict__ fc_w, const float* __restrict__ fc_b,
    const float* __restrict__ ws, float* __restrict__ out)
{
    const int blk = blockIdx.x;
    const int jt = blk & 15, b = blk >> 4;
    const int t = threadIdx.x;
    const int dg = t >> 5, jj = t & 31;
    const int j = jt * 32 + jj;

    __shared__ float hs[512];
    __shared__ float red[8][33];
    __shared__ float osl[32];

    hs[t]       = ws[OFF_HM + (size_t)b * 512 + t];
    hs[t + 256] = ws[OFF_HM + (size_t)b * 512 + t + 256];
    __syncthreads();

    const float* fwp = final_w + (size_t)(dg * 64) * 512 + j;
    const float* hp = hs + dg * 64;
    float acc = 0.f;
    #pragma unroll 8
    for (int d = 0; d < 64; d++)
        acc = fmaf(hp[d], fwp[(size_t)d * 512], acc);
    red[dg][jj] = acc;
    __syncthreads();
    if (t < 32) {
        float s = 0.f;
        #pragma unroll
        for (int q = 0; q < 8; q++) s += red[q][t];
        osl[t] = fmaxf(s + final_b[jt * 32 + t], 0.f);
    }
    __syncthreads();
    if (t < 96) {
        const int l = t >> 5, j2 = t & 31;
        float val = osl[j2] * fc_w[(jt * 32 + j2) * 3 + l];
        #pragma unroll
        for (int off = 16; off > 0; off >>= 1)
            val += __shfl_xor(val, off);
        if (j2 == 0) atomicAdd(out + b * 3 + l, val);
    }
    if (jt == 0 && t < 3) atomicAdd(out + b * 3 + t, fc_b[t]);
}

// ---------------------------------------------------------------------------
extern "C" void kernel_launch(void* const* d_in, const int* in_sizes, int n_in,
                              void* d_out, int out_size, void* d_ws, size_t ws_size,
                              hipStream_t stream)
{
    const float* word    = (const float*)d_in[0];
    const float* rel     = (const float*)d_in[1];
    const float* mask    = (const float*)d_in[2];
    const float* Wn_w    = (const float*)d_in[3];
    const float* Wn_b    = (const float*)d_in[4];
    const float* Wr_w    = (const float*)d_in[5];
    const float* Wr_b    = (const float*)d_in[6];
    const float* lin_w   = (const float*)d_in[7];
    const float* lin_b   = (const float*)d_in[8];
    const float* score_w = (const float*)d_in[9];
    // d_in[10] score_b: cancels in softmax — unused
    const float* final_w = (const float*)d_in[11];
    const float* final_b = (const float*)d_in[12];
    const float* fc_w    = (const float*)d_in[13];
    const float* fc_b    = (const float*)d_in[14];
    float* ws  = (float*)d_ws;
    float* out = (float*)d_out;

    // 4 dispatches, no memsets: out zeroed by proj_gemm (blk 384),
    // hm zeroed by scores_sm — all stream-ordered before their consumers.
    proj_gemm<<<392, 256, 0, stream>>>(word, rel, Wn_w, Wn_b, Wr_w, Wr_b,
                                       lin_w, score_w, ws, out);
    scores_sm<<<256, 256, 0, stream>>>(mask, ws);
    gstep_kernel<<<512, 256, 0, stream>>>(lin_w, lin_b, ws);
    final_logits<<<256, 256, 0, stream>>>(final_w, final_b, fc_w, fc_b, ws, out);
}